// Round 1
// baseline (812.475 us; speedup 1.0000x reference)
//
#include <hip/hip_runtime.h>

// ---------------- problem constants ----------------
#define B_     4
#define T_     512
#define DIN    4096
#define H_     32
#define G_     8
#define HD_    128
#define S_     4096
#define CACHE_ 3584
#define M_     2048          // B*T
#define NQKV   6144          // H*HD + 2*G*HD
#define SCALE  0.08838834764831843f  // 1/sqrt(128)

typedef __attribute__((ext_vector_type(4))) float  f32x4;
typedef __attribute__((ext_vector_type(8))) short  s16x8;   // 8 bf16 (4 VGPRs) MFMA frag
typedef __attribute__((ext_vector_type(4))) unsigned short u16x4;
typedef __attribute__((ext_vector_type(8))) unsigned short u16x8;
typedef unsigned short u16;
typedef unsigned int   u32;

__device__ __forceinline__ u16 f2bf(float f) {
  u32 u = __builtin_bit_cast(u32, f);
  return (u16)((u + 0x7fffu + ((u >> 16) & 1u)) >> 16);   // RNE
}
__device__ __forceinline__ float bf2f(u16 h) {
  return __builtin_bit_cast(float, (u32)h << 16);
}
__device__ __forceinline__ f32x4 mfma16(s16x8 a, s16x8 b, f32x4 c) {
  return __builtin_amdgcn_mfma_f32_16x16x32_bf16(a, b, c, 0, 0, 0);
}

// ---------------- phase 0: x f32 -> bf16 ----------------
__global__ __launch_bounds__(256) void k_cvt_x(const float* __restrict__ x, u16* __restrict__ xb) {
  size_t i = ((size_t)blockIdx.x * 256 + threadIdx.x) * 4;
  f32x4 v = *(const f32x4*)(x + i);
  u16x4 o = { f2bf(v[0]), f2bf(v[1]), f2bf(v[2]), f2bf(v[3]) };
  *(u16x4*)(xb + i) = o;
}

// ---------------- phase 0: weight transpose f32[K][ldn] -> bf16[ldn][4096] ----------------
__global__ __launch_bounds__(256) void k_twt(const float* __restrict__ src, int ldn,
                                             u16* __restrict__ dst) {
  __shared__ float tile[64][68];
  int k0 = blockIdx.x * 64, n0 = blockIdx.y * 64;
  int t = threadIdx.x;
  int rr = t >> 4, cc = (t & 15) * 4;
#pragma unroll
  for (int p = 0; p < 4; ++p) {
    int r = p * 16 + rr;
    f32x4 v = *(const f32x4*)(src + (size_t)(k0 + r) * ldn + n0 + cc);
    tile[r][cc] = v[0]; tile[r][cc + 1] = v[1]; tile[r][cc + 2] = v[2]; tile[r][cc + 3] = v[3];
  }
  __syncthreads();
#pragma unroll
  for (int p = 0; p < 4; ++p) {
    int n = p * 16 + rr;
    u16x4 o = { f2bf(tile[cc][n]), f2bf(tile[cc + 1][n]), f2bf(tile[cc + 2][n]), f2bf(tile[cc + 3][n]) };
    *(u16x4*)(dst + (size_t)(n0 + n) * 4096 + k0 + cc) = o;
  }
}

// ---------------- phase 0: prev_k -> k_all f32 copy + bf16 ----------------
__global__ __launch_bounds__(256) void k_prep_k(const float* __restrict__ pk,
                                                float* __restrict__ k_all, u16* __restrict__ kb) {
  int bg = blockIdx.y;
  size_t si = ((size_t)blockIdx.x * 256 + threadIdx.x) * 4;   // < 3584*128
  f32x4 v = *(const f32x4*)(pk + (size_t)bg * CACHE_ * HD_ + si);
  size_t dof = (size_t)bg * S_ * HD_ + si;
  *(f32x4*)(k_all + dof) = v;
  u16x4 o = { f2bf(v[0]), f2bf(v[1]), f2bf(v[2]), f2bf(v[3]) };
  *(u16x4*)(kb + dof) = o;
}

// ---------------- phase 0: prev_v -> v_all f32 copy + transposed bf16 v_t[bg][hd][s] ----------------
__global__ __launch_bounds__(256) void k_prep_v(const float* __restrict__ pv,
                                                float* __restrict__ v_all, u16* __restrict__ vt) {
  __shared__ float tile[64][132];
  int bg = blockIdx.y, s0 = blockIdx.x * 64;
  int t = threadIdx.x;
  const float* src = pv + ((size_t)bg * CACHE_ + s0) * HD_;
  float* dc = v_all + ((size_t)bg * S_ + s0) * HD_;
  int r8 = t >> 5, c4 = (t & 31) * 4;
#pragma unroll
  for (int p = 0; p < 8; ++p) {
    int r = p * 8 + r8;
    f32x4 v = *(const f32x4*)(src + (size_t)r * HD_ + c4);
    *(f32x4*)(dc + (size_t)r * HD_ + c4) = v;
    tile[r][c4] = v[0]; tile[r][c4 + 1] = v[1]; tile[r][c4 + 2] = v[2]; tile[r][c4 + 3] = v[3];
  }
  __syncthreads();
  int hr = t >> 4, s4 = (t & 15) * 4;
#pragma unroll
  for (int p = 0; p < 8; ++p) {
    int hd = p * 16 + hr;
    u16x4 o = { f2bf(tile[s4][hd]), f2bf(tile[s4 + 1][hd]), f2bf(tile[s4 + 2][hd]), f2bf(tile[s4 + 3][hd]) };
    *(u16x4*)(vt + ((size_t)bg * HD_ + hd) * S_ + s0 + s4) = o;
  }
}

// ---------------- GEMM: C[M][N] = A[M][K]bf16 @ Bt[N][K]bf16 (m97-style 128x128xBK64) ----------------
template<bool OUT_F32>
__global__ __launch_bounds__(256) void k_gemm(const u16* __restrict__ A, const u16* __restrict__ Bt,
                                              void* __restrict__ Cp, int N, int K) {
  __shared__ u16 As[128 * 72];   // [128][64] padded to 72 (row stride 144B, 16B-aligned)
  __shared__ u16 Bs[128 * 72];
  const int tid = threadIdx.x;
  const int m0 = blockIdx.x * 128, n0 = blockIdx.y * 128;
  const int wave = tid >> 6, lane = tid & 63;
  const int wm = (wave >> 1) * 64, wn = (wave & 1) * 64;
  const int cl = lane & 15, kl = (lane >> 4) * 8;
  const int sr = tid >> 3, sc = (tid & 7) * 8;   // staging: row sr within 32-row pass, 8 bf16 cols
  f32x4 acc[4][4] = {};
  for (int k0 = 0; k0 < K; k0 += 64) {
    u16x8 ra[4], rb[4];
#pragma unroll
    for (int i = 0; i < 4; ++i) {
      int r = i * 32 + sr;
      ra[i] = *(const u16x8*)(A + (size_t)(m0 + r) * K + k0 + sc);
      rb[i] = *(const u16x8*)(Bt + (size_t)(n0 + r) * K + k0 + sc);
    }
    __syncthreads();   // previous compute done before LDS overwrite
#pragma unroll
    for (int i = 0; i < 4; ++i) {
      int r = i * 32 + sr;
      *(u16x8*)(As + r * 72 + sc) = ra[i];
      *(u16x8*)(Bs + r * 72 + sc) = rb[i];
    }
    __syncthreads();
#pragma unroll
    for (int kk = 0; kk < 2; ++kk) {
      s16x8 af[4], bfr[4];
#pragma unroll
      for (int mi = 0; mi < 4; ++mi) af[mi]  = *(const s16x8*)(As + (wm + mi * 16 + cl) * 72 + kk * 32 + kl);
#pragma unroll
      for (int ni = 0; ni < 4; ++ni) bfr[ni] = *(const s16x8*)(Bs + (wn + ni * 16 + cl) * 72 + kk * 32 + kl);
#pragma unroll
      for (int mi = 0; mi < 4; ++mi)
#pragma unroll
        for (int ni = 0; ni < 4; ++ni)
          acc[mi][ni] = mfma16(af[mi], bfr[ni], acc[mi][ni]);
    }
  }
  const int rl = (lane >> 4) * 4;
#pragma unroll
  for (int mi = 0; mi < 4; ++mi)
#pragma unroll
    for (int ni = 0; ni < 4; ++ni) {
      int col = n0 + wn + ni * 16 + cl;
#pragma unroll
      for (int r = 0; r < 4; ++r) {
        int rw = m0 + wm + mi * 16 + rl + r;
        if (OUT_F32) ((float*)Cp)[(size_t)rw * N + col] = acc[mi][ni][r];
        else         ((u16*)Cp)[(size_t)rw * N + col]   = f2bf(acc[mi][ni][r]);
      }
    }
}

// ---------------- RoPE + scatter: qkv bf16 -> q_rope bf16, k (roped) -> k_all f32 + k_bf, v -> v_all f32 ----------------
__global__ __launch_bounds__(256) void k_rope(const u16* __restrict__ qkv, const float* __restrict__ cosT,
                                              const float* __restrict__ sinT, const int* __restrict__ sp,
                                              u16* __restrict__ qr, u16* __restrict__ kb,
                                              float* __restrict__ k_all, float* __restrict__ v_all) {
  int bt = blockIdx.x;
  int b = bt >> 9, t = bt & 511;
  int pos = sp[b] + t;
  const u16* row = qkv + (size_t)bt * NQKV;
  for (int idx = threadIdx.x; idx < 2560; idx += 256) {   // 40 roped heads * 64 pairs
    int head = idx >> 6, d = idx & 63;
    float c = cosT[pos * HD_ + d], s = sinT[pos * HD_ + d];
    float x1 = bf2f(row[head * HD_ + d]);
    float x2 = bf2f(row[head * HD_ + d + 64]);
    float y1 = x1 * c - x2 * s;
    float y2 = x2 * c + x1 * s;
    if (head < 32) {
      size_t o = (((size_t)b * H_ + head) * T_ + t) * HD_ + d;
      qr[o] = f2bf(y1); qr[o + 64] = f2bf(y2);
    } else {
      int g = head - 32;
      size_t o = (((size_t)b * G_ + g) * S_ + CACHE_ + t) * HD_ + d;
      kb[o] = f2bf(y1); kb[o + 64] = f2bf(y2);
      k_all[o] = y1; k_all[o + 64] = y2;
    }
  }
  for (int idx = threadIdx.x; idx < 1024; idx += 256) {   // v passthrough (f32 copy only)
    int g = idx >> 7;
    float v = bf2f(row[5120 + idx]);
    size_t o = (((size_t)b * G_ + g) * S_ + CACHE_ + t) * HD_ + (idx & 127);
    v_all[o] = v;
  }
}

// ---------------- transpose new-V slice into v_t[bg][hd][CACHE_..S] ----------------
__global__ __launch_bounds__(256) void k_tv_new(const u16* __restrict__ qkv, u16* __restrict__ vt) {
  __shared__ u16 tile[64][72];
  int bg = blockIdx.y;
  int b = bg >> 3, g = bg & 7;
  int tt = blockIdx.x >> 1, ht = blockIdx.x & 1;
  int t0 = tt * 64, hd0 = ht * 64;
  int t = threadIdx.x;
  int rr = t >> 3, c8 = (t & 7) * 8;
#pragma unroll
  for (int p = 0; p < 2; ++p) {
    int r = p * 32 + rr;
    *(u16x8*)(&tile[r][c8]) =
      *(const u16x8*)(qkv + (size_t)(b * T_ + t0 + r) * NQKV + 5120 + g * HD_ + hd0 + c8);
  }
  __syncthreads();
  int hr = t >> 4, s4 = (t & 15) * 4;
#pragma unroll
  for (int p = 0; p < 4; ++p) {
    int hd = p * 16 + hr;
    u16x4 o = { tile[s4][hd], tile[s4 + 1][hd], tile[s4 + 2][hd], tile[s4 + 3][hd] };
    *(u16x4*)(vt + ((size_t)bg * HD_ + hd0 + hd) * S_ + CACHE_ + t0 + s4) = o;
  }
}

// ---------------- flash attention: 1 block per (qtile64, h, b); 4 waves x 16 q-rows ----------------
__global__ __launch_bounds__(256) void k_attn(const u16* __restrict__ Q, const u16* __restrict__ Kc,
                                              const u16* __restrict__ Vt, const int* __restrict__ sp,
                                              u16* __restrict__ ctx) {
  __shared__ u16 Ks[64 * 136];    // K tile [kv64][hd128] pad->136
  __shared__ u16 Vs[128 * 72];    // V^T tile [hd128][kv64] pad->72
  __shared__ u16 Pl[4 * 16 * 72]; // per-wave P [16][64] pad->72
  const int qt = blockIdx.x, h = blockIdx.y, b = blockIdx.z;
  const int g = h >> 2;           // GS = 4
  const int tid = threadIdx.x, wave = tid >> 6, lane = tid & 63;
  const int cl = lane & 15, kl = (lane >> 4) * 8, rl = (lane >> 4) * 4;
  const int cache = sp[b];
  const size_t kvoff = (size_t)(b * G_ + g) * S_ * HD_;
  const u16* kp = Kc + kvoff;
  const u16* vp = Vt + kvoff;     // v_t slab is also 128*4096 per (b,g)
  s16x8 aq[4];
  {
    const u16* qb = Q + (((size_t)(b * H_ + h)) * T_ + qt * 64 + wave * 16 + cl) * HD_;
#pragma unroll
    for (int kk = 0; kk < 4; ++kk) aq[kk] = *(const s16x8*)(qb + kk * 32 + kl);
  }
  f32x4 acc[8] = {};
  float mr[4] = { -1e30f, -1e30f, -1e30f, -1e30f };
  float ls[4] = { 0.f, 0.f, 0.f, 0.f };
  const int qi0 = qt * 64;
  const int jlast = (cache + qi0 + 63) >> 6;
  const int kr = tid >> 4, kc = (tid & 15) * 8;
  const int vr = tid >> 3, vc = (tid & 7) * 8;
  for (int j = 0; j <= jlast; ++j) {
    u16x8 rk[4], rv[4];
#pragma unroll
    for (int i = 0; i < 4; ++i) {
      rk[i] = *(const u16x8*)(kp + (size_t)(j * 64 + i * 16 + kr) * HD_ + kc);
      rv[i] = *(const u16x8*)(vp + (size_t)(i * 32 + vr) * S_ + j * 64 + vc);
    }
    __syncthreads();
#pragma unroll
    for (int i = 0; i < 4; ++i) {
      *(u16x8*)(Ks + (i * 16 + kr) * 136 + kc) = rk[i];
      *(u16x8*)(Vs + (i * 32 + vr) * 72 + vc) = rv[i];
    }
    __syncthreads();
    // S = Q K^T  (16x64 per wave)
    f32x4 s4v[4] = {};
#pragma unroll
    for (int kk = 0; kk < 4; ++kk)
#pragma unroll
      for (int n = 0; n < 4; ++n) {
        s16x8 bk = *(const s16x8*)(Ks + (n * 16 + cl) * 136 + kk * 32 + kl);
        s4v[n] = mfma16(aq[kk], bk, s4v[n]);
      }
    // scale + causal mask
    float p[4][4];
    float pmax[4] = { -1e30f, -1e30f, -1e30f, -1e30f };
#pragma unroll
    for (int n = 0; n < 4; ++n) {
      int kv = j * 64 + n * 16 + cl;
#pragma unroll
      for (int r = 0; r < 4; ++r) {
        float sv = s4v[n][r] * SCALE;
        int qi = qi0 + wave * 16 + rl + r;
        if (kv > cache + qi) sv = -1e30f;
        p[n][r] = sv;
        pmax[r] = fmaxf(pmax[r], sv);
      }
    }
    float alpha[4];
#pragma unroll
    for (int r = 0; r < 4; ++r) {
      float mx = pmax[r];
      mx = fmaxf(mx, __shfl_xor(mx, 1));
      mx = fmaxf(mx, __shfl_xor(mx, 2));
      mx = fmaxf(mx, __shfl_xor(mx, 4));
      mx = fmaxf(mx, __shfl_xor(mx, 8));
      float mn = fmaxf(mr[r], mx);
      alpha[r] = __expf(mr[r] - mn);
      mr[r] = mn;
    }
    float rsum[4] = { 0.f, 0.f, 0.f, 0.f };
#pragma unroll
    for (int n = 0; n < 4; ++n)
#pragma unroll
      for (int r = 0; r < 4; ++r) {
        float pv = __expf(p[n][r] - mr[r]);
        p[n][r] = pv;
        rsum[r] += pv;
      }
#pragma unroll
    for (int r = 0; r < 4; ++r) {
      float rs = rsum[r];
      rs += __shfl_xor(rs, 1); rs += __shfl_xor(rs, 2);
      rs += __shfl_xor(rs, 4); rs += __shfl_xor(rs, 8);
      ls[r] = ls[r] * alpha[r] + rs;
    }
#pragma unroll
    for (int n = 0; n < 8; ++n)
#pragma unroll
      for (int r = 0; r < 4; ++r) acc[n][r] *= alpha[r];
    // P -> LDS (D-layout to A-layout fix-up)
#pragma unroll
    for (int n = 0; n < 4; ++n)
#pragma unroll
      for (int r = 0; r < 4; ++r)
        Pl[(wave * 16 + rl + r) * 72 + n * 16 + cl] = f2bf(p[n][r]);
    // O += P V
#pragma unroll
    for (int kk2 = 0; kk2 < 2; ++kk2) {
      s16x8 ap = *(const s16x8*)(Pl + (wave * 16 + cl) * 72 + kk2 * 32 + kl);
#pragma unroll
      for (int n = 0; n < 8; ++n) {
        s16x8 bv = *(const s16x8*)(Vs + (n * 16 + cl) * 72 + kk2 * 32 + kl);
        acc[n] = mfma16(ap, bv, acc[n]);
      }
    }
  }
#pragma unroll
  for (int r = 0; r < 4; ++r) {
    float inv = 1.0f / ls[r];
    int qi = qi0 + wave * 16 + rl + r;
    u16* cb = ctx + ((size_t)(b * T_ + qi)) * 4096 + h * HD_;
#pragma unroll
    for (int n = 0; n < 8; ++n) cb[n * 16 + cl] = f2bf(acc[n][r] * inv);
  }
}

// ---------------- launch ----------------
extern "C" void kernel_launch(void* const* d_in, const int* in_sizes, int n_in,
                              void* d_out, int out_size, void* d_ws, size_t ws_size,
                              hipStream_t stream) {
  const float* x      = (const float*)d_in[0];
  // d_in[1] = mask (derived analytically; unused)
  const float* cosT   = (const float*)d_in[2];
  const float* sinT   = (const float*)d_in[3];
  const int*   sp     = (const int*)d_in[4];
  const float* prev_k = (const float*)d_in[5];
  const float* prev_v = (const float*)d_in[6];
  const float* q_w    = (const float*)d_in[7];
  const float* k_w    = (const float*)d_in[8];
  const float* v_w    = (const float*)d_in[9];
  const float* o_w    = (const float*)d_in[10];

  float* out   = (float*)d_out;
  float* k_all = out + (size_t)B_ * T_ * H_ * HD_;      // +8388608
  float* v_all = k_all + (size_t)B_ * G_ * S_ * HD_;    // +16777216

  char* w = (char*)d_ws;
  u16* wt_qkv = (u16*)(w);                 // [6144][4096] bf16   50331648 B
  u16* wt_o   = (u16*)(w + 50331648);      // [4096][4096] bf16   33554432 B
  u16* x_bf   = (u16*)(w + 83886080);      // [2048][4096] bf16   16777216 B
  u16* qkv_bf = (u16*)(w + 100663296);     // [2048][6144] bf16   25165824 B
  u16* q_rope = (u16*)(w + 125829120);     // [4][32][512][128]   16777216 B
  u16* k_bf   = (u16*)(w + 142606336);     // [4][8][4096][128]   33554432 B
  u16* v_t    = (u16*)(w + 176160768);     // [4][8][128][4096]   33554432 B
  u16* ctx    = (u16*)(w + 209715200);     // [2048][4096]        16777216 B
  if (ws_size < 226492416ull) return;      // workspace too small -> bench will flag it

  k_cvt_x<<<8192, 256, 0, stream>>>(x, x_bf);
  k_twt<<<dim3(64, 64), 256, 0, stream>>>(q_w, 4096, wt_qkv);
  k_twt<<<dim3(64, 16), 256, 0, stream>>>(k_w, 1024, wt_qkv + (size_t)4096 * 4096);
  k_twt<<<dim3(64, 16), 256, 0, stream>>>(v_w, 1024, wt_qkv + (size_t)5120 * 4096);
  k_twt<<<dim3(64, 64), 256, 0, stream>>>(o_w, 4096, wt_o);
  k_prep_k<<<dim3(448, 32), 256, 0, stream>>>(prev_k, k_all, k_bf);
  k_prep_v<<<dim3(56, 32), 256, 0, stream>>>(prev_v, v_all, v_t);
  k_gemm<false><<<dim3(16, 48), 256, 0, stream>>>(x_bf, wt_qkv, qkv_bf, NQKV, 4096);
  k_rope<<<2048, 256, 0, stream>>>(qkv_bf, cosT, sinT, sp, q_rope, k_bf, k_all, v_all);
  k_tv_new<<<dim3(16, 32), 256, 0, stream>>>(qkv_bf, v_t);
  k_attn<<<dim3(8, 32, 4), 256, 0, stream>>>(q_rope, k_bf, v_t, sp, ctx);
  k_gemm<true><<<dim3(16, 32), 256, 0, stream>>>(ctx, wt_o, out, 4096, 4096);
}